// Round 8
// baseline (72.062 us; speedup 1.0000x reference)
//
#include <hip/hip_runtime.h>
#include <math.h>

#define DIMC 768
#define BATCH 16
#define HWSZ 1024
#define NT 32
#define SCH 16          // channel splits
#define CHPB 48         // channels per block

// out layout: result [16*32*768] | p [16*32*768] | mask [16*32*1024]
#define OUT_P_OFF    393216
#define OUT_MASK_OFF 786432

// ws layout (floats): partials [16][16][32][1024] | wt [768*32] | pk [768*12]
#define WS_WT_OFF 8388608
#define WS_PK_OFF 8413184

typedef float v4f __attribute__((ext_vector_type(4)));

// ---------------- K0: transpose pww -> wt[c][t]; pack per-channel params ---
// pk[c][12] = { dw[0..8], dw_bias, bn_scale, bn_shift } (48B rows, 16B-aligned)
__global__ __launch_bounds__(256) void k0_prep(
    const float* __restrict__ pww,
    const float* __restrict__ dww, const float* __restrict__ dwb,
    const float* __restrict__ bnw, const float* __restrict__ bnb,
    const float* __restrict__ bnm, const float* __restrict__ bnv,
    float* __restrict__ wt, float* __restrict__ pk)
{
    int i = blockIdx.x * 256 + threadIdx.x;
    if (i < 24576) wt[i] = pww[(i & 31) * DIMC + (i >> 5)];
    int c = i - 24576;
    if (c >= 0 && c < DIMC) {
        float* o = pk + c * 12;
#pragma unroll
        for (int j = 0; j < 9; ++j) o[j] = dww[c * 9 + j];
        o[9] = dwb[c];
        float scale = bnw[c] * rsqrtf(bnv[c] + 1e-5f);
        o[10] = scale;
        o[11] = bnb[c] - bnm[c] * scale;
    }
}

// ---------------- KF: fused BN + dw3x3 + hardswish + pointwise partials ----
// BARRIER-FREE: each wave owns 2 output rows + a private triple-buffered
// 4x34 halo tile in LDS. No __syncthreads in the K-loop -> no vmcnt drain;
// depth-3 register prefetch of x actually stays in flight.
//
// BODY(kc): ds_write ch kc+1 (regs loaded 3 iters ago) -> buf[(kc+1)%3];
//           issue loads ch kc+4 -> same reg slot; conv+hsw+pw ch kc from
//           buf[kc%3]. Unroll x3 with named reg slots (gA/gB/gC).

#define CONVPW(kc, BC)                                                       \
    {                                                                        \
        const float* pr = pkb + (kc) * 12;                                   \
        v4f P0 = *(const v4f*)(pr + 0);                                      \
        v4f P1 = *(const v4f*)(pr + 4);                                      \
        v4f P2 = *(const v4f*)(pr + 8);      /* {w8, dwb, scale, shift} */   \
        const float* S = (BC) + base;                                        \
        float r = P2.y;                                                      \
        r = fmaf(P0.x, S[ 0], r);                                            \
        r = fmaf(P0.y, S[ 1], r);                                            \
        r = fmaf(P0.z, S[ 2], r);                                            \
        r = fmaf(P0.w, S[34], r);                                            \
        r = fmaf(P1.x, S[35], r);                                            \
        r = fmaf(P1.y, S[36], r);                                            \
        r = fmaf(P1.z, S[68], r);                                            \
        r = fmaf(P1.w, S[69], r);                                            \
        r = fmaf(P2.x, S[70], r);                                            \
        float clp = fminf(fmaxf(r + 3.0f, 0.0f), 6.0f);                      \
        float hs  = r * clp * (1.0f / 6.0f);                                 \
        const float* wr_ = wtb + (kc) * NT;                                  \
        v4f hv = {hs, hs, hs, hs};                                           \
        A0 = __builtin_elementwise_fma(hv, *(const v4f*)(wr_ +  0), A0);     \
        A1 = __builtin_elementwise_fma(hv, *(const v4f*)(wr_ +  4), A1);     \
        A2 = __builtin_elementwise_fma(hv, *(const v4f*)(wr_ +  8), A2);     \
        A3 = __builtin_elementwise_fma(hv, *(const v4f*)(wr_ + 12), A3);     \
        A4 = __builtin_elementwise_fma(hv, *(const v4f*)(wr_ + 16), A4);     \
        A5 = __builtin_elementwise_fma(hv, *(const v4f*)(wr_ + 20), A5);     \
        A6 = __builtin_elementwise_fma(hv, *(const v4f*)(wr_ + 24), A6);     \
        A7 = __builtin_elementwise_fma(hv, *(const v4f*)(wr_ + 28), A7);     \
    }

#define BODY(KC, BW, GW, BC)                                                 \
    {                                                                        \
        const int kc = (KC);                                                 \
        if (kc + 1 < CHPB) {          /* write ch kc+1 (loaded 3 iters ago)*/\
            const float* pn = pkb + (kc + 1) * 12;                           \
            float scn = pn[10], shn = pn[11];                                \
            if (va) (BW)[sA] = fmaf(GW##a, scn, shn);                        \
            if (vb) (BW)[sB] = fmaf(GW##b, scn, shn);                        \
            if (vc) (BW)[sC] = fmaf(GW##c, scn, shn);                        \
        }                                                                    \
        {                             /* refill GW with ch kc+4 (clamped) */ \
            int cp = (kc + 4 < CHPB) ? kc + 4 : 0;                           \
            const float* xc = xb + (size_t)cp * HWSZ;                        \
            if (va) GW##a = xc[oa];                                          \
            if (vb) GW##b = xc[ob];                                          \
            if (vc) GW##c = xc[oc];                                          \
        }                                                                    \
        CONVPW(kc, BC)                                                       \
    }

__global__ __launch_bounds__(256) void kf_fused(
    const float* __restrict__ x,
    const float* __restrict__ wt, const float* __restrict__ pk,
    float* __restrict__ partials)
{
    const int b    = blockIdx.z;
    const int scc  = blockIdx.y;
    const int cb0  = scc * CHPB;
    const int r0   = blockIdx.x * 8;          // block covers 8 output rows
    const int tid  = threadIdx.x;
    const int wv   = tid >> 6;                // wave 0..3
    const int lane = tid & 63;
    const int rl   = lane >> 5;               // local output row 0..1
    const int col  = lane & 31;

    __shared__ float st[4][3][136];           // wave-private triple buffers
    float* wbuf0 = &st[wv][0][0];
    float* wbuf1 = &st[wv][1][0];
    float* wbuf2 = &st[wv][2][0];

    // zero this wave's buffers (halo slots are never rewritten)
    for (int j = lane; j < 408; j += 64) wbuf0[j] = 0.0f;

    // slot geometry: wave tile is 4 rows x 34 cols (data rows wr0-1..wr0+2)
    const int wr0 = r0 + 2 * wv;
    const int sA = lane, sB = lane + 64, sC = lane + 128;
    int oa, ob, oc; bool va, vb, vc;
    {
        int sr = sA / 34, sc2 = sA - sr * 34;
        int gr = wr0 - 1 + sr, gc = sc2 - 1;
        va = gr >= 0 && gr < 32 && gc >= 0 && gc < 32; oa = gr * 32 + gc;
    }
    {
        int sr = sB / 34, sc2 = sB - sr * 34;
        int gr = wr0 - 1 + sr, gc = sc2 - 1;
        vb = gr >= 0 && gr < 32 && gc >= 0 && gc < 32; ob = gr * 32 + gc;
    }
    {
        int sr = sC / 34, sc2 = sC - sr * 34;
        int gr = wr0 - 1 + sr, gc = sc2 - 1;
        vc = (sC < 136) && gr >= 0 && gr < 32 && gc >= 0 && gc < 32;
        oc = gr * 32 + gc;
    }

    const float* xb  = x  + (size_t)(b * DIMC + cb0) * HWSZ;
    const float* pkb = pk + (size_t)cb0 * 12;
    const float* wtb = wt + (size_t)cb0 * NT;

    // prologue: stage ch0 into buf0 (BN applied); prime ch1/ch2/ch3 regs
    {
        const v4f P2 = *(const v4f*)(pkb + 8);
        if (va) wbuf0[sA] = fmaf(xb[oa], P2.z, P2.w);
        if (vb) wbuf0[sB] = fmaf(xb[ob], P2.z, P2.w);
        if (vc) wbuf0[sC] = fmaf(xb[oc], P2.z, P2.w);
    }
    float gBa = 0.f, gBb = 0.f, gBc = 0.f;    // slot 1 -> ch1
    float gCa = 0.f, gCb = 0.f, gCc = 0.f;    // slot 2 -> ch2
    float gAa = 0.f, gAb = 0.f, gAc = 0.f;    // slot 0 -> ch3
    if (va) gBa = xb[(size_t)1 * HWSZ + oa];
    if (vb) gBb = xb[(size_t)1 * HWSZ + ob];
    if (vc) gBc = xb[(size_t)1 * HWSZ + oc];
    if (va) gCa = xb[(size_t)2 * HWSZ + oa];
    if (vb) gCb = xb[(size_t)2 * HWSZ + ob];
    if (vc) gCc = xb[(size_t)2 * HWSZ + oc];
    if (va) gAa = xb[(size_t)3 * HWSZ + oa];
    if (vb) gAb = xb[(size_t)3 * HWSZ + ob];
    if (vc) gAc = xb[(size_t)3 * HWSZ + oc];

    v4f A0 = {0,0,0,0}, A1 = {0,0,0,0}, A2 = {0,0,0,0}, A3 = {0,0,0,0};
    v4f A4 = {0,0,0,0}, A5 = {0,0,0,0}, A6 = {0,0,0,0}, A7 = {0,0,0,0};
    const int base = rl * 34 + col;

    for (int k = 0; k < CHPB; k += 3) {
        BODY(k + 0, wbuf1, gB, wbuf0)
        BODY(k + 1, wbuf2, gC, wbuf1)
        BODY(k + 2, wbuf0, gA, wbuf2)
    }

    // epilogue: 32 token-partials; pos = r0*32 + wv*64 + lane = bx*256 + tid
    float* po = partials + ((size_t)(scc * BATCH + b) * NT) * HWSZ
              + blockIdx.x * 256 + tid;
    po[ 0 << 10] = A0.x; po[ 1 << 10] = A0.y; po[ 2 << 10] = A0.z; po[ 3 << 10] = A0.w;
    po[ 4 << 10] = A1.x; po[ 5 << 10] = A1.y; po[ 6 << 10] = A1.z; po[ 7 << 10] = A1.w;
    po[ 8 << 10] = A2.x; po[ 9 << 10] = A2.y; po[10 << 10] = A2.z; po[11 << 10] = A2.w;
    po[12 << 10] = A3.x; po[13 << 10] = A3.y; po[14 << 10] = A3.z; po[15 << 10] = A3.w;
    po[16 << 10] = A4.x; po[17 << 10] = A4.y; po[18 << 10] = A4.z; po[19 << 10] = A4.w;
    po[20 << 10] = A5.x; po[21 << 10] = A5.y; po[22 << 10] = A5.z; po[23 << 10] = A5.w;
    po[24 << 10] = A6.x; po[25 << 10] = A6.y; po[26 << 10] = A6.z; po[27 << 10] = A6.w;
    po[28 << 10] = A7.x; po[29 << 10] = A7.y; po[30 << 10] = A7.z; po[31 << 10] = A7.w;
}

// ---------------- K3: sum partials -> argmax mask -> gather-sum ------------
__global__ __launch_bounds__(256) void k3_mask_gather(
    const float* __restrict__ partials,
    const float* __restrict__ x, const float* __restrict__ posin,
    const float* __restrict__ bnw, const float* __restrict__ bnb,
    const float* __restrict__ bnm, const float* __restrict__ bnv,
    float* __restrict__ out)
{
    int bt = blockIdx.x;           // b*32 + t
    int b  = bt >> 5;
    int t  = bt & 31;
    int tid = threadIdx.x;

    const float4* pp4 = (const float4*)(partials + ((size_t)(b * NT) + t) * HWSZ) + tid;
    float4 acc = make_float4(0.f, 0.f, 0.f, 0.f);
#pragma unroll
    for (int s = 0; s < SCH; ++s) {
        float4 u = pp4[(size_t)s * (BATCH * NT * HWSZ / 4)];
        acc.x += u.x; acc.y += u.y; acc.z += u.z; acc.w += u.w;
    }

    float m = fmaxf(fmaxf(acc.x, acc.y), fmaxf(acc.z, acc.w));
#pragma unroll
    for (int off = 32; off; off >>= 1)
        m = fmaxf(m, __shfl_xor(m, off));
    __shared__ float wm[4];
    if ((tid & 63) == 0) wm[tid >> 6] = m;
    __syncthreads();
    m = fmaxf(fmaxf(wm[0], wm[1]), fmaxf(wm[2], wm[3]));

    __shared__ int nmatch;
    __shared__ int matchpos[16];
    if (tid == 0) nmatch = 0;
    __syncthreads();

    float* maskp = out + OUT_MASK_OFF + (size_t)bt * HWSZ;
    float4 mask4;
    const float* av = &acc.x;
    float* mv = &mask4.x;
#pragma unroll
    for (int j = 0; j < 4; ++j) {
        int hit = (av[j] == m);
        mv[j] = hit ? 1.0f : 0.0f;
        if (hit) {
            int k = atomicAdd(&nmatch, 1);
            if (k < 16) matchpos[k] = 4 * tid + j;
        }
    }
    ((float4*)maskp)[tid] = mask4;
    __syncthreads();
    int nm = nmatch < 16 ? nmatch : 16;

    const float* xb = x + (size_t)b * DIMC * HWSZ;
    const float* pb = posin + (size_t)b * DIMC * HWSZ;
    for (int c = tid; c < DIMC; c += 256) {
        float scale = bnw[c] * rsqrtf(bnv[c] + 1e-5f);
        float shift = bnb[c] - bnm[c] * scale;
        float rf = 0.0f, rp = 0.0f;
        for (int k = 0; k < nm; ++k) {
            int pos = matchpos[k];
            rf += xb[(size_t)c * HWSZ + pos] * scale + shift;
            rp += pb[(size_t)c * HWSZ + pos];
        }
        out[(size_t)bt * DIMC + c] = rf;
        out[OUT_P_OFF + (size_t)bt * DIMC + c] = rp;
    }
}

extern "C" void kernel_launch(void* const* d_in, const int* in_sizes, int n_in,
                              void* d_out, int out_size, void* d_ws, size_t ws_size,
                              hipStream_t stream)
{
    const float* x    = (const float*)d_in[0];
    const float* pos  = (const float*)d_in[1];
    const float* bnw  = (const float*)d_in[2];
    const float* bnb  = (const float*)d_in[3];
    const float* bnm  = (const float*)d_in[4];
    const float* bnv  = (const float*)d_in[5];
    const float* dww  = (const float*)d_in[6];
    const float* dwb  = (const float*)d_in[7];
    const float* pww  = (const float*)d_in[8];
    // d_in[9] (pw_bias) unused: constant per (b,t) row -> outputs invariant.
    float* out = (float*)d_out;

    float* partials = (float*)d_ws;
    float* wt       = (float*)d_ws + WS_WT_OFF;
    float* pk       = (float*)d_ws + WS_PK_OFF;

    k0_prep<<<99, 256, 0, stream>>>(pww, dww, dwb, bnw, bnb, bnm, bnv, wt, pk);
    kf_fused<<<dim3(4, SCH, BATCH), 256, 0, stream>>>(x, wt, pk, partials);
    k3_mask_gather<<<BATCH * NT, 256, 0, stream>>>(partials, x, pos,
                                                   bnw, bnb, bnm, bnv, out);
}